// Round 1
// baseline (20895.930 us; speedup 1.0000x reference)
//
#include <hip/hip_runtime.h>

typedef unsigned short u16;
typedef unsigned int u32;
using bf16x8 = __attribute__((ext_vector_type(8))) short;
using f32x4  = __attribute__((ext_vector_type(4))) float;

#define TT   256
#define NB   64
#define XDI  256
#define HDI  512
#define ZDI  128
#define VV   10000
#define NWGB 32

// ---- workspace byte offsets (all 512-aligned) ----
#define OFF_CTRL  0ull
#define OFF_WE1   512ull        // [512][768] bf16
#define OFF_WE2   786944ull     // [512][512] bf16
#define OFF_WMW   1311232ull    // [128][512] bf16
#define OFF_WSW   1442304ull    // [128][512] bf16
#define OFF_WD1   1573376ull    // [512][640] bf16
#define OFF_WD2   2228736ull    // [512][512] bf16
#define OFF_WDM   2753024ull    // [256][512] bf16
#define OFF_WIH   3015168ull    // [1536][384] bf16
#define OFF_WHH   4194816ull    // [1536][512] bf16
#define OFF_WGW   5767680ull    // [10000][256] bf16
#define OFF_XEMB  10887680ull   // [256][64][256] bf16
#define OFF_H     19276288ull   // [64][512] f32
#define OFF_HB    19407360ull   // [64][512] bf16
#define OFF_C1B   19472896ull   // [64][512] bf16
#define OFF_EB    19538432ull   // [64][512] bf16
#define OFF_GH    19603968ull   // [64][1536] f32
#define OFF_ZALL  19997184ull   // [256*64][128] bf16
#define OFF_HALL  24191488ull   // [256*64][512] bf16  (h_{t-1})
#define OFF_GPART 40968704ull   // [256] f32

__device__ __forceinline__ u16 f2b(float f) {
  union { float f; u32 u; } v; v.f = f;
  u32 r = v.u + 0x7fffu + ((v.u >> 16) & 1u);
  return (u16)(r >> 16);
}

__device__ __forceinline__ void gridbar(int* cnt, int target) {
  __syncthreads();
  if (threadIdx.x == 0) {
    __hip_atomic_fetch_add(cnt, 1, __ATOMIC_RELEASE, __HIP_MEMORY_SCOPE_AGENT);
    while (__hip_atomic_load(cnt, __ATOMIC_ACQUIRE, __HIP_MEMORY_SCOPE_AGENT) < target)
      __builtin_amdgcn_s_sleep(2);
  }
  __syncthreads();
}

// fill LDS A[64][Ktot] (bf16, byte ^ ((row&7)<<4) swizzle) from two row-major bf16 sources
__device__ __forceinline__ void fill_lds(u16* lds, int Ktot,
                                         const u16* s0, int K0,
                                         const u16* s1, int K1) {
  int kch = Ktot >> 3;
  int nch = 64 * kch;
  for (int i = threadIdx.x; i < nch; i += 256) {
    int row = i / kch;
    int k = (i - row * kch) << 3;
    const u16* src = (k < K0) ? (s0 + row * K0 + k) : (s1 + row * K1 + (k - K0));
    uint4 v = *(const uint4*)src;
    int byte = ((row * Ktot + k) << 1) ^ ((row & 7) << 4);
    *(uint4*)((char*)lds + byte) = v;
  }
}

// 64xK (LDS, swizzled) @ W[O][Kw]^T -> 64x16 tile at cols [wcol0, wcol0+16)
__device__ __forceinline__ void mm_tile(f32x4 acc[4], const u16* lds, int ldsStride, int ldsK0,
                                        const u16* __restrict__ W, int Kw, int wcol0,
                                        int Klen, int lane) {
  const int kl = (lane >> 4) << 3;
  const int cl = lane & 15;
  const u16* wp = W + (size_t)(wcol0 + cl) * Kw;
  for (int kc = 0; kc < Klen; kc += 32) {
    int k = kc + kl;
    bf16x8 b = *(const bf16x8*)(wp + k);
#pragma unroll
    for (int m = 0; m < 4; ++m) {
      int row = (m << 4) + cl;
      int byte = ((row * ldsStride + ldsK0 + k) << 1) ^ ((row & 7) << 4);
      bf16x8 a = *(const bf16x8*)((const char*)lds + byte);
      acc[m] = __builtin_amdgcn_mfma_f32_16x16x32_bf16(a, b, acc[m], 0, 0, 0);
    }
  }
}

// ---------------- prep kernels ----------------
struct ConvArgs { const float* s[10]; unsigned long long doff[10]; int n[10]; };

__global__ __launch_bounds__(256) void wconv(char* ws, ConvArgs a) {
  int seg = blockIdx.y;
  const float* s = a.s[seg];
  u16* d = (u16*)(ws + a.doff[seg]);
  int n = a.n[seg];
  int i = (blockIdx.x * 256 + threadIdx.x) * 8;
  if (i < n) {
    float4 v0 = *(const float4*)(s + i);
    float4 v1 = *(const float4*)(s + i + 4);
    uint4 o;
    o.x = (u32)f2b(v0.x) | ((u32)f2b(v0.y) << 16);
    o.y = (u32)f2b(v0.z) | ((u32)f2b(v0.w) << 16);
    o.z = (u32)f2b(v1.x) | ((u32)f2b(v1.y) << 16);
    o.w = (u32)f2b(v1.z) | ((u32)f2b(v1.w) << 16);
    *(uint4*)(d + i) = o;
  }
}

__global__ __launch_bounds__(256) void gatherx(char* ws, const int* xs, const float* embed) {
  u16* xemb = (u16*)(ws + OFF_XEMB);
  int i = blockIdx.x * 256 + threadIdx.x;        // 524288 chunks of 8
  int t = i >> 11;
  int rr = i & 2047;
  int n = rr >> 5;
  int k = (rr & 31) << 3;
  int idx = xs[n * TT + t];
  const float* src = embed + (size_t)idx * XDI + k;
  float4 v0 = *(const float4*)src;
  float4 v1 = *(const float4*)(src + 4);
  uint4 o;
  o.x = (u32)f2b(v0.x) | ((u32)f2b(v0.y) << 16);
  o.y = (u32)f2b(v0.z) | ((u32)f2b(v0.w) << 16);
  o.z = (u32)f2b(v1.x) | ((u32)f2b(v1.y) << 16);
  o.w = (u32)f2b(v1.z) | ((u32)f2b(v1.w) << 16);
  *(uint4*)(xemb + ((size_t)t * NB + n) * XDI + k) = o;
}

__global__ __launch_bounds__(256) void h0init(char* ws, const int* labels, const int* wflag,
                                              const float* hnoise, const float* hw, const float* hb0) {
  int i = blockIdx.x * 256 + threadIdx.x;        // 32768
  int n = i >> 9, c = i & 511;
  float v = (float)labels[n] * hw[c] + hb0[c];
  if (wflag[0]) v += hnoise[i];
  ((float*)(ws + OFF_H))[i] = v;
  ((u16*)(ws + OFF_HB))[i] = f2b(v);
}

// ---------------- phase B: sequential recurrence ----------------
__global__ __launch_bounds__(256, 1) void phaseB(
    char* ws, const float* eps, const float* b_e1, const float* b_e2,
    const float* b_mw, const float* b_sw, const float* bih, const float* bhh) {
  __shared__ u16 lA[64 * 768];  // 96 KiB
  const u16* we1 = (const u16*)(ws + OFF_WE1);
  const u16* we2 = (const u16*)(ws + OFF_WE2);
  const u16* wmw = (const u16*)(ws + OFF_WMW);
  const u16* wsw = (const u16*)(ws + OFF_WSW);
  const u16* wih = (const u16*)(ws + OFF_WIH);
  const u16* whh = (const u16*)(ws + OFF_WHH);
  const u16* xemb = (const u16*)(ws + OFF_XEMB);
  float* h = (float*)(ws + OFF_H);
  u16* hb = (u16*)(ws + OFF_HB);
  u16* c1b = (u16*)(ws + OFF_C1B);
  u16* eb = (u16*)(ws + OFF_EB);
  float* gh = (float*)(ws + OFF_GH);
  u16* zall = (u16*)(ws + OFF_ZALL);
  u16* hall = (u16*)(ws + OFF_HALL);
  int* cnt = (int*)(ws + OFF_CTRL);

  int tid = threadIdx.x, wave = tid >> 6, lane = tid & 63;
  int wg = blockIdx.x;
  int tl = (wg << 2) + wave;
  int bphase = 0;

  for (int t = 0; t < TT; ++t) {
    const u16* xe = xemb + (size_t)t * NB * XDI;
    // ---- stage 1: c1 = relu([x|h]@We1^T + b1);  gh = h@Whh^T + bhh ----
    fill_lds(lA, 768, xe, 256, hb, 512);
    __syncthreads();
    if (tl < 32) {
      f32x4 acc[4];
      acc[0] = acc[1] = acc[2] = acc[3] = (f32x4){0.f, 0.f, 0.f, 0.f};
      mm_tile(acc, lA, 768, 0, we1, 768, tl * 16, 768, lane);
      int col = tl * 16 + (lane & 15);
      float bias = b_e1[col];
#pragma unroll
      for (int m = 0; m < 4; ++m)
#pragma unroll
        for (int j = 0; j < 4; ++j) {
          int row = (m << 4) + ((lane >> 4) << 2) + j;
          c1b[row * 512 + col] = f2b(fmaxf(acc[m][j] + bias, 0.f));
        }
    } else {
      int g = tl - 32;
      f32x4 acc[4];
      acc[0] = acc[1] = acc[2] = acc[3] = (f32x4){0.f, 0.f, 0.f, 0.f};
      mm_tile(acc, lA, 768, 256, whh, 512, g * 16, 512, lane);
      int col = g * 16 + (lane & 15);
      float bias = bhh[col];
#pragma unroll
      for (int m = 0; m < 4; ++m)
#pragma unroll
        for (int j = 0; j < 4; ++j) {
          int row = (m << 4) + ((lane >> 4) << 2) + j;
          gh[row * 1536 + col] = acc[m][j] + bias;
        }
    }
    gridbar(cnt, ++bphase * NWGB);
    // ---- stage 2: e = relu(c1@We2^T + b2) ----
    if (wg < 8) {
      fill_lds(lA, 512, c1b, 512, c1b, 512);
      __syncthreads();
      f32x4 acc[4];
      acc[0] = acc[1] = acc[2] = acc[3] = (f32x4){0.f, 0.f, 0.f, 0.f};
      mm_tile(acc, lA, 512, 0, we2, 512, tl * 16, 512, lane);
      int col = tl * 16 + (lane & 15);
      float bias = b_e2[col];
#pragma unroll
      for (int m = 0; m < 4; ++m)
#pragma unroll
        for (int j = 0; j < 4; ++j) {
          int row = (m << 4) + ((lane >> 4) << 2) + j;
          eb[row * 512 + col] = f2b(fmaxf(acc[m][j] + bias, 0.f));
        }
    }
    gridbar(cnt, ++bphase * NWGB);
    // ---- stage 3: z = eps*softplus(e@Ws^T+bs) + (e@Wm^T+bm) ----
    if (wg < 2) {
      fill_lds(lA, 512, eb, 512, eb, 512);
      __syncthreads();
      f32x4 aM[4], aS[4];
      aM[0] = aM[1] = aM[2] = aM[3] = (f32x4){0.f, 0.f, 0.f, 0.f};
      aS[0] = aS[1] = aS[2] = aS[3] = (f32x4){0.f, 0.f, 0.f, 0.f};
      mm_tile(aM, lA, 512, 0, wmw, 512, tl * 16, 512, lane);
      mm_tile(aS, lA, 512, 0, wsw, 512, tl * 16, 512, lane);
      int col = tl * 16 + (lane & 15);
      float mb = b_mw[col], sb = b_sw[col];
#pragma unroll
      for (int m = 0; m < 4; ++m)
#pragma unroll
        for (int j = 0; j < 4; ++j) {
          int row = (m << 4) + ((lane >> 4) << 2) + j;
          float mu = aM[m][j] + mb;
          float sx = aS[m][j] + sb;
          float sp = fmaxf(sx, 0.f) + log1pf(__expf(-fabsf(sx)));
          float ev = eps[row * (TT * ZDI) + t * ZDI + col];
          zall[((size_t)t * NB + row) * ZDI + col] = f2b(ev * sp + mu);
        }
    }
    gridbar(cnt, ++bphase * NWGB);
    // ---- stage 4: gi = [x|z]@Wih^T + bih; gates; h' ----
    if (wg < 8) {
      fill_lds(lA, 384, xe, 256, zall + (size_t)t * NB * ZDI, 128);
      __syncthreads();
      f32x4 aR[4], aZ[4], aN[4];
      aR[0] = aR[1] = aR[2] = aR[3] = (f32x4){0.f, 0.f, 0.f, 0.f};
      aZ[0] = aZ[1] = aZ[2] = aZ[3] = (f32x4){0.f, 0.f, 0.f, 0.f};
      aN[0] = aN[1] = aN[2] = aN[3] = (f32x4){0.f, 0.f, 0.f, 0.f};
      mm_tile(aR, lA, 384, 0, wih, 384, tl * 16, 384, lane);
      mm_tile(aZ, lA, 384, 0, wih, 384, tl * 16 + 512, 384, lane);
      mm_tile(aN, lA, 384, 0, wih, 384, tl * 16 + 1024, 384, lane);
      int col = tl * 16 + (lane & 15);
      float bR = bih[col], bZ = bih[col + 512], bN = bih[col + 1024];
#pragma unroll
      for (int m = 0; m < 4; ++m)
#pragma unroll
        for (int j = 0; j < 4; ++j) {
          int row = (m << 4) + ((lane >> 4) << 2) + j;
          float ir = aR[m][j] + bR, iz = aZ[m][j] + bZ, inn = aN[m][j] + bN;
          float hr = gh[row * 1536 + col];
          float hz = gh[row * 1536 + col + 512];
          float hn = gh[row * 1536 + col + 1024];
          float rg = 1.f / (1.f + __expf(-(ir + hr)));
          float zg = 1.f / (1.f + __expf(-(iz + hz)));
          float ng = tanhf(inn + rg * hn);
          float hold = h[row * 512 + col];
          float hnew = (1.f - zg) * ng + zg * hold;
          hall[((size_t)t * NB + row) * HDI + col] = f2b(hold);
          h[row * 512 + col] = hnew;
          hb[row * 512 + col] = f2b(hnew);
        }
    }
    gridbar(cnt, ++bphase * NWGB);
  }
}

// ---------------- phase C: decoder chain + generation loss (per 64-row block) ----------------
__global__ __launch_bounds__(256, 1) void phaseC(
    char* ws, const float* db1, const float* db2, const float* dmbias,
    const float* genb, const int* ts, float* gpart) {
  __shared__ u16 lA[64 * 640];  // 80 KiB
  __shared__ u16 lB[64 * 512];  // 64 KiB
  int rb = blockIdx.x;          // rb == timestep t; rows are batch n
  int tid = threadIdx.x, wave = tid >> 6, lane = tid & 63;
  const u16* zall = (const u16*)(ws + OFF_ZALL);
  const u16* hall = (const u16*)(ws + OFF_HALL);
  const u16* wd1 = (const u16*)(ws + OFF_WD1);
  const u16* wd2 = (const u16*)(ws + OFF_WD2);
  const u16* wdm = (const u16*)(ws + OFF_WDM);
  const u16* wgw = (const u16*)(ws + OFF_WGW);

  fill_lds(lA, 640, zall + (size_t)rb * NB * ZDI, 128, hall + (size_t)rb * NB * HDI, 512);
  __syncthreads();
  // dec1 -> lB (stride 512)
  for (int tile = wave; tile < 32; tile += 4) {
    f32x4 acc[4];
    acc[0] = acc[1] = acc[2] = acc[3] = (f32x4){0.f, 0.f, 0.f, 0.f};
    mm_tile(acc, lA, 640, 0, wd1, 640, tile * 16, 640, lane);
    int col = tile * 16 + (lane & 15);
    float bias = db1[col];
#pragma unroll
    for (int m = 0; m < 4; ++m)
#pragma unroll
      for (int j = 0; j < 4; ++j) {
        int row = (m << 4) + ((lane >> 4) << 2) + j;
        int byte = ((row * 512 + col) << 1) ^ ((row & 7) << 4);
        *(u16*)((char*)lB + byte) = f2b(fmaxf(acc[m][j] + bias, 0.f));
      }
  }
  __syncthreads();
  // dec2 -> lA (stride 512)
  for (int tile = wave; tile < 32; tile += 4) {
    f32x4 acc[4];
    acc[0] = acc[1] = acc[2] = acc[3] = (f32x4){0.f, 0.f, 0.f, 0.f};
    mm_tile(acc, lB, 512, 0, wd2, 512, tile * 16, 512, lane);
    int col = tile * 16 + (lane & 15);
    float bias = db2[col];
#pragma unroll
    for (int m = 0; m < 4; ++m)
#pragma unroll
      for (int j = 0; j < 4; ++j) {
        int row = (m << 4) + ((lane >> 4) << 2) + j;
        int byte = ((row * 512 + col) << 1) ^ ((row & 7) << 4);
        *(u16*)((char*)lA + byte) = f2b(fmaxf(acc[m][j] + bias, 0.f));
      }
  }
  __syncthreads();
  // dec_mean = sigmoid -> lB (stride 256)
  for (int tile = wave; tile < 16; tile += 4) {
    f32x4 acc[4];
    acc[0] = acc[1] = acc[2] = acc[3] = (f32x4){0.f, 0.f, 0.f, 0.f};
    mm_tile(acc, lA, 512, 0, wdm, 512, tile * 16, 512, lane);
    int col = tile * 16 + (lane & 15);
    float bias = dmbias[col];
#pragma unroll
    for (int m = 0; m < 4; ++m)
#pragma unroll
      for (int j = 0; j < 4; ++j) {
        int row = (m << 4) + ((lane >> 4) << 2) + j;
        float v = 1.f / (1.f + __expf(-(acc[m][j] + bias)));
        int byte = ((row * 256 + col) << 1) ^ ((row & 7) << 4);
        *(u16*)((char*)lB + byte) = f2b(v);
      }
  }
  __syncthreads();
  // generation logits + online log-softmax + target gather
  float mr[16], sr[16], cap[16];
  int tg[16];
#pragma unroll
  for (int q = 0; q < 16; ++q) {
    int r = ((q >> 2) << 4) + ((lane >> 4) << 2) + (q & 3);
    tg[q] = ts[r * TT + rb];
    mr[q] = -1e30f; sr[q] = 0.f; cap[q] = -1e30f;
  }
  for (int ct = wave; ct < 625; ct += 4) {
    f32x4 acc[4];
    acc[0] = acc[1] = acc[2] = acc[3] = (f32x4){0.f, 0.f, 0.f, 0.f};
    mm_tile(acc, lB, 256, 0, wgw, 256, ct * 16, 256, lane);
    int colw = ct * 16 + (lane & 15);
    float gbv = genb[colw];
#pragma unroll
    for (int mi = 0; mi < 4; ++mi)
#pragma unroll
      for (int j = 0; j < 4; ++j) {
        int q = (mi << 2) + j;
        float v = acc[mi][j] + gbv;
        if (colw == tg[q]) cap[q] = v;
        float mn = fmaxf(mr[q], v);
        sr[q] = sr[q] * __expf(mr[q] - mn) + __expf(v - mn);
        mr[q] = mn;
      }
  }
#pragma unroll
  for (int d = 1; d < 16; d <<= 1) {
#pragma unroll
    for (int q = 0; q < 16; ++q) {
      float mo = __shfl_xor(mr[q], d);
      float so = __shfl_xor(sr[q], d);
      float co = __shfl_xor(cap[q], d);
      float mn = fmaxf(mr[q], mo);
      sr[q] = sr[q] * __expf(mr[q] - mn) + so * __expf(mo - mn);
      mr[q] = mn;
      cap[q] = fmaxf(cap[q], co);
    }
  }
  float* sc = (float*)lA;  // [3][4][64]
  if ((lane & 15) == 0) {
    int g = lane >> 4;
#pragma unroll
    for (int q = 0; q < 16; ++q) {
      int r = ((q >> 2) << 4) + (g << 2) + (q & 3);
      sc[wave * 64 + r] = mr[q];
      sc[256 + wave * 64 + r] = sr[q];
      sc[512 + wave * 64 + r] = cap[q];
    }
  }
  __syncthreads();
  if (tid < 64) {
    float M = -1e30f, S = 0.f, C = -1e30f;
#pragma unroll
    for (int w = 0; w < 4; ++w) {
      float m = sc[w * 64 + tid], s = sc[256 + w * 64 + tid], c = sc[512 + w * 64 + tid];
      float mn = fmaxf(M, m);
      S = S * __expf(M - mn) + s * __expf(m - mn);
      M = mn;
      C = fmaxf(C, c);
    }
    float lossr = M + __logf(S) - C;
    for (int d = 1; d < 64; d <<= 1) lossr += __shfl_xor(lossr, d);
    if (tid == 0) gpart[rb] = lossr;
  }
}

// ---------------- final: reduce gen partials + classifier loss ----------------
__global__ __launch_bounds__(256) void finalk(char* ws, const int* labels,
                                              const float* cw, const float* cb,
                                              const float* gpart, float* out) {
  __shared__ float sred[256];
  __shared__ float cred[64];
  int tid = threadIdx.x;
  sred[tid] = gpart[tid];
  __syncthreads();
  for (int s2 = 128; s2 > 0; s2 >>= 1) {
    if (tid < s2) sred[tid] += sred[tid + s2];
    __syncthreads();
  }
  const float* h = (const float*)(ws + OFF_H);
  if (tid < 64) {
    const float* hrow = h + tid * 512;
    float a0 = cb[0], a1 = cb[1], a2 = cb[2], a3 = cb[3];
    for (int k = 0; k < 512; k += 4) {
      float4 hv = *(const float4*)(hrow + k);
      float4 w0 = *(const float4*)(cw + 0 * 512 + k);
      float4 w1 = *(const float4*)(cw + 1 * 512 + k);
      float4 w2 = *(const float4*)(cw + 2 * 512 + k);
      float4 w3 = *(const float4*)(cw + 3 * 512 + k);
      a0 += hv.x * w0.x + hv.y * w0.y + hv.z * w0.z + hv.w * w0.w;
      a1 += hv.x * w1.x + hv.y * w1.y + hv.z * w1.z + hv.w * w1.w;
      a2 += hv.x * w2.x + hv.y * w2.y + hv.z * w2.z + hv.w * w2.w;
      a3 += hv.x * w3.x + hv.y * w3.y + hv.z * w3.z + hv.w * w3.w;
    }
    float M = fmaxf(fmaxf(a0, a1), fmaxf(a2, a3));
    float S = __expf(a0 - M) + __expf(a1 - M) + __expf(a2 - M) + __expf(a3 - M);
    int lb = labels[tid];
    float lg = (lb == 0) ? a0 : (lb == 1) ? a1 : (lb == 2) ? a2 : a3;
    cred[tid] = M + __logf(S) - lg;
  }
  __syncthreads();
  if (tid == 0) {
    float cs = 0.f;
    for (int i = 0; i < 64; ++i) cs += cred[i];
    out[0] = sred[0] / 16384.f;
    out[1] = cs / 64.f;
  }
}

extern "C" void kernel_launch(void* const* d_in, const int* in_sizes, int n_in,
                              void* d_out, int out_size, void* d_ws, size_t ws_size,
                              hipStream_t stream) {
  (void)in_sizes; (void)n_in; (void)out_size; (void)ws_size;
  char* ws = (char*)d_ws;
  const int* xs = (const int*)d_in[0];
  const int* ts = (const int*)d_in[1];
  const int* labels = (const int*)d_in[2];
  const int* wflag = (const int*)d_in[3];
  const float* eps = (const float*)d_in[4];
  const float* hnoise = (const float*)d_in[5];
  const float* embed = (const float*)d_in[6];
  const float* e_w1 = (const float*)d_in[7];
  const float* e_b1 = (const float*)d_in[8];
  const float* e_w2 = (const float*)d_in[9];
  const float* e_b2 = (const float*)d_in[10];
  const float* m_w = (const float*)d_in[11];
  const float* m_b = (const float*)d_in[12];
  const float* s_w = (const float*)d_in[13];
  const float* s_b = (const float*)d_in[14];
  const float* d_w1 = (const float*)d_in[15];
  const float* d_b1 = (const float*)d_in[16];
  const float* d_w2 = (const float*)d_in[17];
  const float* d_b2 = (const float*)d_in[18];
  const float* dm_w = (const float*)d_in[19];
  const float* dm_b = (const float*)d_in[20];
  const float* g_ih = (const float*)d_in[21];
  const float* g_hh = (const float*)d_in[22];
  const float* g_bih = (const float*)d_in[23];
  const float* g_bhh = (const float*)d_in[24];
  const float* gw = (const float*)d_in[25];
  const float* gb = (const float*)d_in[26];
  const float* cw = (const float*)d_in[27];
  const float* cb = (const float*)d_in[28];
  const float* hw = (const float*)d_in[29];
  const float* hb0 = (const float*)d_in[30];

  hipMemsetAsync(ws + OFF_CTRL, 0, 512, stream);

  ConvArgs ca;
  const float* srcs[10] = {e_w1, e_w2, m_w, s_w, d_w1, d_w2, dm_w, g_ih, g_hh, gw};
  unsigned long long doffs[10] = {OFF_WE1, OFF_WE2, OFF_WMW, OFF_WSW, OFF_WD1,
                                  OFF_WD2, OFF_WDM, OFF_WIH, OFF_WHH, OFF_WGW};
  int ns[10] = {393216, 262144, 65536, 65536, 327680, 262144, 131072, 589824, 786432, 2560000};
  for (int i = 0; i < 10; ++i) { ca.s[i] = srcs[i]; ca.doff[i] = doffs[i]; ca.n[i] = ns[i]; }

  wconv<<<dim3(1250, 10), 256, 0, stream>>>(ws, ca);
  gatherx<<<2048, 256, 0, stream>>>(ws, xs, embed);
  h0init<<<128, 256, 0, stream>>>(ws, labels, wflag, hnoise, hw, hb0);
  phaseB<<<NWGB, 256, 0, stream>>>(ws, eps, e_b1, e_b2, m_b, s_b, g_bih, g_bhh);
  phaseC<<<256, 256, 0, stream>>>(ws, d_b1, d_b2, dm_b, gb, ts, (float*)(ws + OFF_GPART));
  finalk<<<1, 256, 0, stream>>>(ws, labels, cw, cb, (const float*)(ws + OFF_GPART), (float*)d_out);
}